// Round 9
// baseline (33.881 us; speedup 1.0000x reference)
//
#include <hip/hip_runtime.h>

#define B_  1024
#define I_  512
#define O_  512
#define E_  16
#define K_  8192   // E_*I_ (W flattened as [8192][512] row-major)

#define BK 64
#define NSTEP (I_ / BK)   // 8 K-steps (K = I_ = 512)
#define BM 128
#define BN 64
#define NWG  (E_ * (B_ / BM) * (O_ / BN))   // 16 * 8 * 8 = 1024 blocks

typedef __attribute__((ext_vector_type(8))) short short8;
typedef __attribute__((ext_vector_type(8))) unsigned short ushort8;
typedef __attribute__((ext_vector_type(4))) unsigned short ushort4v;
typedef __attribute__((ext_vector_type(4))) float f32x4;

__device__ __forceinline__ unsigned short f2bf(float f) {
  union { float f; unsigned u; } v; v.f = f;
  unsigned r = v.u + 0x7fffu + ((v.u >> 16) & 1u);
  return (unsigned short)(r >> 16);
}
__device__ __forceinline__ float bf2f(unsigned short h) {
  union { unsigned u; float f; } v; v.u = ((unsigned)h) << 16;
  return v.f;
}

__device__ __forceinline__ void gload_lds16(const unsigned short* g, unsigned short* l) {
  __builtin_amdgcn_global_load_lds(
      (const __attribute__((address_space(1))) void*)g,
      (__attribute__((address_space(3))) void*)l, 16, 0, 0);
}

// Fused prep: blocks [0,256) cast x -> bf16; blocks [256,1280) transpose
// W [8192][512] fp32 -> Wt [512(o)][8192(k=e*512+i)] bf16 via LDS 64x64 tiles.
__global__ void prep_kernel(const float* __restrict__ x,
                            const float* __restrict__ W,
                            unsigned short* __restrict__ xb,
                            unsigned short* __restrict__ Wt) {
  __shared__ unsigned short tile[64][68];  // 136B stride: 8B-aligned writes
  if (blockIdx.x < 256) {
    int base = (blockIdx.x * 256 + threadIdx.x) * 8;
    const float4* xp = (const float4*)(x + base);
    float4 v0 = xp[0], v1 = xp[1];
    ushort8 r;
    r[0] = f2bf(v0.x); r[1] = f2bf(v0.y); r[2] = f2bf(v0.z); r[3] = f2bf(v0.w);
    r[4] = f2bf(v1.x); r[5] = f2bf(v1.y); r[6] = f2bf(v1.z); r[7] = f2bf(v1.w);
    *(ushort8*)(xb + base) = r;
  } else {
    int bw = blockIdx.x - 256;
    int kt = (bw & 127) << 6;   // along k (8192/64 = 128)
    int nt = (bw >> 7) << 6;    // along o (512/64 = 8)
    int t = threadIdx.x;
#pragma unroll
    for (int it = 0; it < 4; ++it) {
      int r = it * 16 + (t >> 4);
      int c4 = (t & 15) * 4;
      float4 v = *(const float4*)(W + (long)(kt + r) * O_ + nt + c4);
      ushort4v u;
      u[0] = f2bf(v.x); u[1] = f2bf(v.y); u[2] = f2bf(v.z); u[3] = f2bf(v.w);
      *(ushort4v*)(&tile[r][c4]) = u;
    }
    __syncthreads();
#pragma unroll
    for (int it = 0; it < 2; ++it) {
      int idx = it * 256 + t;
      int r2 = idx >> 3;            // o-row within tile
      int c2 = (idx & 7) * 8;       // k base within tile
      ushort8 v;
#pragma unroll
      for (int j = 0; j < 8; ++j) v[j] = tile[c2 + j][r2];
      *(ushort8*)(Wt + (long)(nt + r2) * K_ + kt + c2) = v;
    }
  }
}

// fallback-mode bias init (atomic path)
__global__ void bias_init_kernel(const float* __restrict__ coeffs,
                                 const float* __restrict__ eb,
                                 float* __restrict__ out) {
  int t = blockIdx.x * 256 + threadIdx.x;
  int b = t >> 7;
  int o4 = (t & 127) * 4;
  const float* cb = coeffs + b * E_;
  float4 acc = {0.f, 0.f, 0.f, 0.f};
#pragma unroll
  for (int e = 0; e < E_; ++e) {
    float c = cb[e];
    float4 bv = *(const float4*)(eb + e * O_ + o4);
    acc.x += c * bv.x; acc.y += c * bv.y; acc.z += c * bv.z; acc.w += c * bv.w;
  }
  *(float4*)(out + b * O_ + o4) = acc;
}

// Per-expert GEMM: P[e][1024][512] = xb @ Wt(e-slice)^T.
// 128x64 tile, BK=64, 48 KB LDS -> 3 blocks/CU co-resident (grid 1024),
// round-3-proven 2-phase dbuf schedule (__syncthreads, prefetch-before-compute),
// T2 XOR-swizzle (pre-swizzled global source + swizzled ds_read), XCD swizzle.
template <int USE_PART>
__global__ __launch_bounds__(256) void gemm_kernel(
    const unsigned short* __restrict__ xb,
    const unsigned short* __restrict__ Wt,
    const float* __restrict__ coeffs,
    float* __restrict__ out,
    unsigned short* __restrict__ part) {
  __shared__ unsigned short As[2][BM * BK];   // 16 KB per buf
  __shared__ unsigned short Bs[2][BN * BK];   //  8 KB per buf
  // XCD-aware bijective swizzle: nwg=1024 (%8==0) -> swz=(bx&7)*128+(bx>>3).
  // Each XCD owns 128 consecutive swz = 2 experts (64 tiles each): Wt slice
  // (1 MiB) + xb (1 MiB) stay L2-resident per XCD.
  int bx = blockIdx.x;
  int swz = (bx & 7) * (NWG / 8) + (bx >> 3);
  int e = swz >> 6;                  // 64 tiles per expert
  int tm = (swz >> 3) & 7, tn = swz & 7;
  int brow = tm * BM, bcol = tn * BN;

  int tid = threadIdx.x;
  int lane = tid & 63, wave = tid >> 6;
  int wr = wave >> 1, wc = wave & 1;   // wave tile: 64(M) x 32(N)

  f32x4 acc[4][2];
#pragma unroll
  for (int m = 0; m < 4; ++m)
#pragma unroll
    for (int n = 0; n < 2; ++n) acc[m][n] = (f32x4){0.f, 0.f, 0.f, 0.f};

  // staging: row-within-8-chunk = lane>>3, 16B piece j = lane&7.
  // Pre-swizzle k so LDS holds elem k at byte (k*2 ^ ((row&7)<<4)).
  int lr8 = lane >> 3;
  int jj = lane & 7;
  int ksrc = (jj ^ lr8) * 8;
  const unsigned short* gA = xb + (long)(brow + lr8) * I_ + ksrc;
  const unsigned short* gB = Wt + (long)(bcol + lr8) * K_ + e * I_ + ksrc;

  auto STAGE = [&](int buf, int s) {   // 24 chunks (16 A + 8 B), 6 per wave
    long kof = (long)s * BK;
#pragma unroll
    for (int i = 0; i < 6; ++i) {
      int chunk = i * 4 + wave;        // wave-uniform; i-groups don't straddle 16
      if (chunk < 16)
        gload_lds16(gA + (long)chunk * 8 * I_ + kof, &As[buf][chunk * 512]);
      else
        gload_lds16(gB + (long)(chunk - 16) * 8 * K_ + kof, &Bs[buf][(chunk - 16) * 512]);
    }
  };

  auto COMPUTE = [&](int buf) {
#pragma unroll
    for (int kk = 0; kk < 2; ++kk) {
      int kbyte = kk * 64 + (lane >> 4) * 16;  // byte offset of 8 bf16 along K
      short8 af[4], bfr[2];
#pragma unroll
      for (int m = 0; m < 4; ++m) {
        int r = wr * 64 + m * 16 + (lane & 15);
        int off = r * 64 + ((kbyte ^ ((r & 7) << 4)) >> 1);
        af[m] = *(const short8*)(&As[buf][off]);
      }
#pragma unroll
      for (int n = 0; n < 2; ++n) {
        int r = wc * 32 + n * 16 + (lane & 15);
        int off = r * 64 + ((kbyte ^ ((r & 7) << 4)) >> 1);
        bfr[n] = *(const short8*)(&Bs[buf][off]);
      }
#pragma unroll
      for (int m = 0; m < 4; ++m)
#pragma unroll
        for (int n = 0; n < 2; ++n)
          acc[m][n] = __builtin_amdgcn_mfma_f32_16x16x32_bf16(af[m], bfr[n], acc[m][n], 0, 0, 0);
    }
  };

  STAGE(0, 0);
  __syncthreads();
#pragma unroll
  for (int s = 0; s < NSTEP; ++s) {
    if (s + 1 < NSTEP) STAGE((s + 1) & 1, s + 1);  // prefetch BEFORE compute
    COMPUTE(s & 1);
    __syncthreads();
  }

  // C/D layout: col = lane&15, row = (lane>>4)*4 + reg
  int crow = wr * 64 + (lane >> 4) * 4;
  int ccol = wc * 32 + (lane & 15);
  if (USE_PART) {
    unsigned short* pb = part + (long)e * B_ * O_;
#pragma unroll
    for (int m = 0; m < 4; ++m)
#pragma unroll
      for (int n = 0; n < 2; ++n) {
        long rbase = (long)(brow + crow + m * 16) * O_ + bcol + ccol + n * 16;
#pragma unroll
        for (int j = 0; j < 4; ++j)
          pb[rbase + (long)j * O_] = f2bf(acc[m][n][j]);
      }
  } else {
    // atomic fallback: weight by c[row,e] here
#pragma unroll
    for (int m = 0; m < 4; ++m)
#pragma unroll
      for (int n = 0; n < 2; ++n) {
#pragma unroll
        for (int j = 0; j < 4; ++j) {
          int row = brow + crow + m * 16 + j;
          float c = coeffs[row * E_ + e];
          atomicAdd(out + (long)row * O_ + bcol + ccol + n * 16, c * acc[m][n][j]);
        }
      }
  }
}

// out[b][o] = sum_e c[b,e] * (P[e][b][o] + bias[e][o]); 8 outputs/thread, 16B loads
__global__ void combine_kernel(const unsigned short* __restrict__ part,
                               const float* __restrict__ coeffs,
                               const float* __restrict__ eb,
                               float* __restrict__ out) {
  int t = blockIdx.x * 256 + threadIdx.x;   // 65536 threads
  int b = t >> 6;
  int o8 = (t & 63) * 8;
  const float* cb = coeffs + b * E_;
  float acc[8] = {0.f, 0.f, 0.f, 0.f, 0.f, 0.f, 0.f, 0.f};
#pragma unroll
  for (int e = 0; e < E_; ++e) {
    float c = cb[e];
    ushort8 v = *(const ushort8*)(part + (long)e * B_ * O_ + (long)b * O_ + o8);
#pragma unroll
    for (int j = 0; j < 8; ++j) acc[j] += c * bf2f(v[j]);
    float4 b0 = *(const float4*)(eb + e * O_ + o8);
    float4 b1 = *(const float4*)(eb + e * O_ + o8 + 4);
    acc[0] += c * b0.x; acc[1] += c * b0.y; acc[2] += c * b0.z; acc[3] += c * b0.w;
    acc[4] += c * b1.x; acc[5] += c * b1.y; acc[6] += c * b1.z; acc[7] += c * b1.w;
  }
  float4 r0 = {acc[0], acc[1], acc[2], acc[3]};
  float4 r1 = {acc[4], acc[5], acc[6], acc[7]};
  *(float4*)(out + (long)b * O_ + o8) = r0;
  *(float4*)(out + (long)b * O_ + o8 + 4) = r1;
}

extern "C" void kernel_launch(void* const* d_in, const int* in_sizes, int n_in,
                              void* d_out, int out_size, void* d_ws, size_t ws_size,
                              hipStream_t stream) {
  const float* x      = (const float*)d_in[0];
  const float* coeffs = (const float*)d_in[1];
  const float* W      = (const float*)d_in[2];
  const float* eb     = (const float*)d_in[3];
  float* out = (float*)d_out;

  size_t xb_bytes   = (size_t)B_ * I_ * 2;        //  1 MiB
  size_t Wt_bytes   = (size_t)O_ * K_ * 2;        //  8 MiB
  size_t part_bytes = (size_t)E_ * B_ * O_ * 2;   // 16 MiB
  unsigned short* xb   = (unsigned short*)d_ws;
  unsigned short* Wt   = (unsigned short*)((char*)d_ws + xb_bytes);
  unsigned short* part = (unsigned short*)((char*)d_ws + xb_bytes + Wt_bytes);
  bool use_part = ws_size >= xb_bytes + Wt_bytes + part_bytes;

  prep_kernel<<<dim3(256 + 1024), 256, 0, stream>>>(x, W, xb, Wt);
  if (use_part) {
    gemm_kernel<1><<<dim3(NWG), 256, 0, stream>>>(xb, Wt, coeffs, out, part);
    combine_kernel<<<dim3(B_ * O_ / 8 / 256), 256, 0, stream>>>(part, coeffs, eb, out);
  } else {
    bias_init_kernel<<<dim3(B_ * O_ / 4 / 256), 256, 0, stream>>>(coeffs, eb, out);
    gemm_kernel<0><<<dim3(NWG), 256, 0, stream>>>(xb, Wt, coeffs, out, part);
  }
}

// Round 11
// 31.804 us; speedup vs baseline: 1.0653x; 1.0653x over previous
//
#include <hip/hip_runtime.h>

#define B_  1024
#define I_  512
#define O_  512
#define E_  16
#define K_  8192   // E_*I_ (W flattened as [8192][512] row-major)

#define BK 64
#define NSTEP (I_ / BK)   // 8 K-steps of the per-expert GEMM (K = I_ = 512)
#define NWG  (E_ * (B_ / 128) * (O_ / 128))   // 16 * 8 * 4 = 512 blocks

typedef __attribute__((ext_vector_type(8))) short short8;
typedef __attribute__((ext_vector_type(8))) unsigned short ushort8;
typedef __attribute__((ext_vector_type(4))) unsigned short ushort4v;
typedef __attribute__((ext_vector_type(4))) float f32x4;

__device__ __forceinline__ unsigned short f2bf(float f) {
  union { float f; unsigned u; } v; v.f = f;
  unsigned r = v.u + 0x7fffu + ((v.u >> 16) & 1u);
  return (unsigned short)(r >> 16);
}
__device__ __forceinline__ float bf2f(unsigned short h) {
  union { unsigned u; float f; } v; v.u = ((unsigned)h) << 16;
  return v.f;
}

__device__ __forceinline__ void gload_lds16(const unsigned short* g, unsigned short* l) {
  __builtin_amdgcn_global_load_lds(
      (const __attribute__((address_space(1))) void*)g,
      (__attribute__((address_space(3))) void*)l, 16, 0, 0);
}

// Fused prep: blocks [0,256) cast x -> bf16; blocks [256,1280) transpose
// W [8192][512] fp32 -> Wt [512(o)][8192(k=e*512+i)] bf16 via LDS 64x64 tiles.
// (round-3 version: float4 W loads, 68-short padded rows)
__global__ void prep_kernel(const float* __restrict__ x,
                            const float* __restrict__ W,
                            unsigned short* __restrict__ xb,
                            unsigned short* __restrict__ Wt) {
  __shared__ unsigned short tile[64][68];  // 136B stride: 8B-aligned writes
  if (blockIdx.x < 256) {
    int base = (blockIdx.x * 256 + threadIdx.x) * 8;
    const float4* xp = (const float4*)(x + base);
    float4 v0 = xp[0], v1 = xp[1];
    ushort8 r;
    r[0] = f2bf(v0.x); r[1] = f2bf(v0.y); r[2] = f2bf(v0.z); r[3] = f2bf(v0.w);
    r[4] = f2bf(v1.x); r[5] = f2bf(v1.y); r[6] = f2bf(v1.z); r[7] = f2bf(v1.w);
    *(ushort8*)(xb + base) = r;
  } else {
    int bw = blockIdx.x - 256;
    int kt = (bw & 127) << 6;   // along k (8192/64 = 128)
    int nt = (bw >> 7) << 6;    // along o (512/64 = 8)
    int t = threadIdx.x;
#pragma unroll
    for (int it = 0; it < 4; ++it) {
      int r = it * 16 + (t >> 4);
      int c4 = (t & 15) * 4;
      float4 v = *(const float4*)(W + (long)(kt + r) * O_ + nt + c4);
      ushort4v u;
      u[0] = f2bf(v.x); u[1] = f2bf(v.y); u[2] = f2bf(v.z); u[3] = f2bf(v.w);
      *(ushort4v*)(&tile[r][c4]) = u;
    }
    __syncthreads();
#pragma unroll
    for (int it = 0; it < 2; ++it) {
      int idx = it * 256 + t;
      int r2 = idx >> 3;            // o-row within tile
      int c2 = (idx & 7) * 8;       // k base within tile
      ushort8 v;
#pragma unroll
      for (int j = 0; j < 8; ++j) v[j] = tile[c2 + j][r2];
      *(ushort8*)(Wt + (long)(nt + r2) * K_ + kt + c2) = v;
    }
  }
}

// fallback-mode bias init (atomic path)
__global__ void bias_init_kernel(const float* __restrict__ coeffs,
                                 const float* __restrict__ eb,
                                 float* __restrict__ out) {
  int t = blockIdx.x * 256 + threadIdx.x;
  int b = t >> 7;
  int o4 = (t & 127) * 4;
  const float* cb = coeffs + b * E_;
  float4 acc = {0.f, 0.f, 0.f, 0.f};
#pragma unroll
  for (int e = 0; e < E_; ++e) {
    float c = cb[e];
    float4 bv = *(const float4*)(eb + e * O_ + o4);
    acc.x += c * bv.x; acc.y += c * bv.y; acc.z += c * bv.z; acc.w += c * bv.w;
  }
  *(float4*)(out + b * O_ + o4) = acc;
}

// Per-expert GEMM: P[e][1024][512] = xb[1024][512] @ Wt(e-slice)^T.
// 128x128 tile, BK=64, double-buffered LDS, 2-phase pipeline
// (__syncthreads schedule — round-2/round-3 proven best), T2 XOR-swizzle
// (pre-swizzled global source + swizzled ds_read), bijective XCD swizzle.
template <int USE_PART>
__global__ __launch_bounds__(256) void gemm_kernel(
    const unsigned short* __restrict__ xb,
    const unsigned short* __restrict__ Wt,
    const float* __restrict__ coeffs,
    float* __restrict__ out,
    unsigned short* __restrict__ part) {
  __shared__ unsigned short As[2][128 * 64];
  __shared__ unsigned short Bs[2][128 * 64];
  // XCD-aware bijective swizzle: nwg=512, 512%8==0 -> swz=(bx%8)*64+bx/8.
  // XCD x then owns experts {2x,2x+1}: Wt slice (1MB) + xb (1MB) L2-resident.
  int bx = blockIdx.x;
  int swz = (bx & 7) * (NWG / 8) + (bx >> 3);
  int e = swz >> 5;
  int tile = swz & 31;
  int tm = tile >> 2, tn = tile & 3;
  int brow = tm * 128, bcol = tn * 128;

  int tid = threadIdx.x;
  int lane = tid & 63, wave = tid >> 6;
  int wr = wave >> 1, wc = wave & 1;

  f32x4 acc[4][4];
#pragma unroll
  for (int m = 0; m < 4; ++m)
#pragma unroll
    for (int n = 0; n < 4; ++n) acc[m][n] = (f32x4){0.f, 0.f, 0.f, 0.f};

  // staging: row-within-chunk = lane>>3, 16B piece j = lane&7.
  // Pre-swizzle k so LDS holds elem k at byte (k*2 ^ ((row&7)<<4)).
  int lr8 = lane >> 3;
  int jj = lane & 7;
  int ksrc = (jj ^ lr8) * 8;
  const unsigned short* gA = xb + (long)(brow + lr8) * I_ + ksrc;
  const unsigned short* gB = Wt + (long)(bcol + lr8) * K_ + e * I_ + ksrc;

  auto STAGE = [&](int buf, int s) {
    long kof = (long)s * BK;
#pragma unroll
    for (int i = 0; i < 4; ++i) {
      int chunk = i * 4 + wave;  // wave-uniform LDS base
      gload_lds16(gA + (long)chunk * 8 * I_ + kof, &As[buf][chunk * 512]);
      gload_lds16(gB + (long)chunk * 8 * K_ + kof, &Bs[buf][chunk * 512]);
    }
  };

  auto COMPUTE = [&](int buf) {
#pragma unroll
    for (int kk = 0; kk < 2; ++kk) {
      int kbyte = kk * 64 + (lane >> 4) * 16;  // byte offset of 8 bf16 along K
      short8 af[4], bfr[4];
#pragma unroll
      for (int m = 0; m < 4; ++m) {
        int r = wr * 64 + m * 16 + (lane & 15);
        int off = r * 64 + ((kbyte ^ ((r & 7) << 4)) >> 1);
        af[m] = *(const short8*)(&As[buf][off]);
      }
#pragma unroll
      for (int n = 0; n < 4; ++n) {
        int r = wc * 64 + n * 16 + (lane & 15);
        int off = r * 64 + ((kbyte ^ ((r & 7) << 4)) >> 1);
        bfr[n] = *(const short8*)(&Bs[buf][off]);
      }
#pragma unroll
      for (int m = 0; m < 4; ++m)
#pragma unroll
        for (int n = 0; n < 4; ++n)
          acc[m][n] = __builtin_amdgcn_mfma_f32_16x16x32_bf16(af[m], bfr[n], acc[m][n], 0, 0, 0);
    }
  };

  STAGE(0, 0);
  __syncthreads();
#pragma unroll
  for (int s = 0; s < NSTEP; ++s) {
    if (s + 1 < NSTEP) STAGE((s + 1) & 1, s + 1);  // prefetch BEFORE compute
    COMPUTE(s & 1);
    __syncthreads();
  }

  // C/D layout: col = lane&15, row = (lane>>4)*4 + reg
  int crow = wr * 64 + (lane >> 4) * 4;
  int ccol = wc * 64 + (lane & 15);
  if (USE_PART) {
    unsigned short* pb = part + (long)e * B_ * O_;
#pragma unroll
    for (int m = 0; m < 4; ++m)
#pragma unroll
      for (int n = 0; n < 4; ++n) {
        long rbase = (long)(brow + crow + m * 16) * O_ + bcol + ccol + n * 16;
#pragma unroll
        for (int j = 0; j < 4; ++j)
          pb[rbase + (long)j * O_] = f2bf(acc[m][n][j]);
      }
  } else {
    // atomic fallback: weight by c[row,e] here
#pragma unroll
    for (int m = 0; m < 4; ++m)
#pragma unroll
      for (int n = 0; n < 4; ++n) {
#pragma unroll
        for (int j = 0; j < 4; ++j) {
          int row = brow + crow + m * 16 + j;
          float c = coeffs[row * E_ + e];
          atomicAdd(out + (long)row * O_ + bcol + ccol + n * 16, c * acc[m][n][j]);
        }
      }
  }
}

// out[b][o] = sum_e c[b,e] * (P[e][b][o] + bias[e][o]); 8 outputs/thread, 16B loads
// (round-3 version)
__global__ void combine_kernel(const unsigned short* __restrict__ part,
                               const float* __restrict__ coeffs,
                               const float* __restrict__ eb,
                               float* __restrict__ out) {
  int t = blockIdx.x * 256 + threadIdx.x;   // 65536 threads
  int b = t >> 6;
  int o8 = (t & 63) * 8;
  const float* cb = coeffs + b * E_;
  float acc[8] = {0.f, 0.f, 0.f, 0.f, 0.f, 0.f, 0.f, 0.f};
#pragma unroll
  for (int e = 0; e < E_; ++e) {
    float c = cb[e];
    ushort8 v = *(const ushort8*)(part + (long)e * B_ * O_ + (long)b * O_ + o8);
#pragma unroll
    for (int j = 0; j < 8; ++j) acc[j] += c * bf2f(v[j]);
    float4 b0 = *(const float4*)(eb + e * O_ + o8);
    float4 b1 = *(const float4*)(eb + e * O_ + o8 + 4);
    acc[0] += c * b0.x; acc[1] += c * b0.y; acc[2] += c * b0.z; acc[3] += c * b0.w;
    acc[4] += c * b1.x; acc[5] += c * b1.y; acc[6] += c * b1.z; acc[7] += c * b1.w;
  }
  float4 r0 = {acc[0], acc[1], acc[2], acc[3]};
  float4 r1 = {acc[4], acc[5], acc[6], acc[7]};
  *(float4*)(out + (long)b * O_ + o8) = r0;
  *(float4*)(out + (long)b * O_ + o8 + 4) = r1;
}

extern "C" void kernel_launch(void* const* d_in, const int* in_sizes, int n_in,
                              void* d_out, int out_size, void* d_ws, size_t ws_size,
                              hipStream_t stream) {
  const float* x      = (const float*)d_in[0];
  const float* coeffs = (const float*)d_in[1];
  const float* W      = (const float*)d_in[2];
  const float* eb     = (const float*)d_in[3];
  float* out = (float*)d_out;

  size_t xb_bytes   = (size_t)B_ * I_ * 2;        //  1 MiB
  size_t Wt_bytes   = (size_t)O_ * K_ * 2;        //  8 MiB
  size_t part_bytes = (size_t)E_ * B_ * O_ * 2;   // 16 MiB
  unsigned short* xb   = (unsigned short*)d_ws;
  unsigned short* Wt   = (unsigned short*)((char*)d_ws + xb_bytes);
  unsigned short* part = (unsigned short*)((char*)d_ws + xb_bytes + Wt_bytes);
  bool use_part = ws_size >= xb_bytes + Wt_bytes + part_bytes;

  prep_kernel<<<dim3(256 + 1024), 256, 0, stream>>>(x, W, xb, Wt);
  if (use_part) {
    gemm_kernel<1><<<dim3(NWG), 256, 0, stream>>>(xb, Wt, coeffs, out, part);
    combine_kernel<<<dim3(B_ * O_ / 8 / 256), 256, 0, stream>>>(part, coeffs, eb, out);
  } else {
    bias_init_kernel<<<dim3(B_ * O_ / 4 / 256), 256, 0, stream>>>(coeffs, eb, out);
    gemm_kernel<0><<<dim3(NWG), 256, 0, stream>>>(xb, Wt, coeffs, out, part);
  }
}

// Round 12
// 30.058 us; speedup vs baseline: 1.1272x; 1.0581x over previous
//
#include <hip/hip_runtime.h>

#define B_  1024
#define I_  512
#define O_  512
#define E_  16
#define K_  8192   // E_*I_ (W flattened as [8192][512] row-major)

#define BK 64
#define NSTEP (I_ / BK)   // 8 K-steps of the per-expert GEMM (K = I_ = 512)
#define NWG  (E_ * (B_ / 128) * (O_ / 128))   // 16 * 8 * 4 = 512 blocks

typedef __attribute__((ext_vector_type(8))) short short8;
typedef __attribute__((ext_vector_type(8))) unsigned short ushort8;
typedef __attribute__((ext_vector_type(4))) unsigned short ushort4v;
typedef __attribute__((ext_vector_type(4))) float f32x4;

__device__ __forceinline__ unsigned short f2bf(float f) {
  union { float f; unsigned u; } v; v.f = f;
  unsigned r = v.u + 0x7fffu + ((v.u >> 16) & 1u);
  return (unsigned short)(r >> 16);
}
__device__ __forceinline__ float bf2f(unsigned short h) {
  union { unsigned u; float f; } v; v.u = ((unsigned)h) << 16;
  return v.f;
}

__device__ __forceinline__ void gload_lds16(const unsigned short* g, unsigned short* l) {
  __builtin_amdgcn_global_load_lds(
      (const __attribute__((address_space(1))) void*)g,
      (__attribute__((address_space(3))) void*)l, 16, 0, 0);
}

// Fused prep: blocks [0,256) cast x -> bf16; blocks [256,1280) transpose
// W [8192][512] fp32 -> Wt [512(o)][8192(k=e*512+i)] bf16 via LDS 64x64 tiles.
// (round-3-measured-best version: scalar W loads, 65-short padded rows)
__global__ void prep_kernel(const float* __restrict__ x,
                            const float* __restrict__ W,
                            unsigned short* __restrict__ xb,
                            unsigned short* __restrict__ Wt) {
  __shared__ unsigned short tile[64][65];
  if (blockIdx.x < 256) {
    int base = (blockIdx.x * 256 + threadIdx.x) * 8;
    const float4* xp = (const float4*)(x + base);
    float4 v0 = xp[0], v1 = xp[1];
    ushort8 r;
    r[0] = f2bf(v0.x); r[1] = f2bf(v0.y); r[2] = f2bf(v0.z); r[3] = f2bf(v0.w);
    r[4] = f2bf(v1.x); r[5] = f2bf(v1.y); r[6] = f2bf(v1.z); r[7] = f2bf(v1.w);
    *(ushort8*)(xb + base) = r;
  } else {
    int bw = blockIdx.x - 256;
    int kt = (bw & 127) << 6;   // along k (8192/64 = 128)
    int nt = (bw >> 7) << 6;    // along o (512/64 = 8)
    int t = threadIdx.x;
#pragma unroll
    for (int it = 0; it < 16; ++it) {
      int idx = it * 256 + t;
      int r = idx >> 6, c = idx & 63;
      tile[r][c] = f2bf(W[(long)(kt + r) * O_ + nt + c]);
    }
    __syncthreads();
#pragma unroll
    for (int it = 0; it < 2; ++it) {
      int idx = it * 256 + t;
      int r2 = idx >> 3;            // o-row within tile
      int c2 = (idx & 7) * 8;       // k base within tile
      ushort8 v;
#pragma unroll
      for (int j = 0; j < 8; ++j) v[j] = tile[c2 + j][r2];
      *(ushort8*)(Wt + (long)(nt + r2) * K_ + kt + c2) = v;
    }
  }
}

// fallback-mode bias init (atomic path)
__global__ void bias_init_kernel(const float* __restrict__ coeffs,
                                 const float* __restrict__ eb,
                                 float* __restrict__ out) {
  int t = blockIdx.x * 256 + threadIdx.x;
  int b = t >> 7;
  int o4 = (t & 127) * 4;
  const float* cb = coeffs + b * E_;
  float4 acc = {0.f, 0.f, 0.f, 0.f};
#pragma unroll
  for (int e = 0; e < E_; ++e) {
    float c = cb[e];
    float4 bv = *(const float4*)(eb + e * O_ + o4);
    acc.x += c * bv.x; acc.y += c * bv.y; acc.z += c * bv.z; acc.w += c * bv.w;
  }
  *(float4*)(out + b * O_ + o4) = acc;
}

// Per-expert GEMM: P[e][1024][512] = xb[1024][512] @ Wt(e-slice)^T.
// 128x128 tile, BK=64, double-buffered LDS, 2-phase pipeline, T2 XOR-swizzle
// (pre-swizzled global source + swizzled ds_read), bijective XCD swizzle.
template <int USE_PART>
__global__ __launch_bounds__(256) void gemm_kernel(
    const unsigned short* __restrict__ xb,
    const unsigned short* __restrict__ Wt,
    const float* __restrict__ coeffs,
    float* __restrict__ out,
    unsigned short* __restrict__ part) {
  __shared__ unsigned short As[2][128 * 64];
  __shared__ unsigned short Bs[2][128 * 64];
  // XCD-aware bijective swizzle: nwg=512, 512%8==0 -> swz=(bx%8)*64+bx/8.
  // XCD x then owns experts {2x,2x+1}: Wt slice (1MB) + xb (1MB) L2-resident.
  int bx = blockIdx.x;
  int swz = (bx & 7) * (NWG / 8) + (bx >> 3);
  int e = swz >> 5;
  int tile = swz & 31;
  int tm = tile >> 2, tn = tile & 3;
  int brow = tm * 128, bcol = tn * 128;

  int tid = threadIdx.x;
  int lane = tid & 63, wave = tid >> 6;
  int wr = wave >> 1, wc = wave & 1;

  f32x4 acc[4][4];
#pragma unroll
  for (int m = 0; m < 4; ++m)
#pragma unroll
    for (int n = 0; n < 4; ++n) acc[m][n] = (f32x4){0.f, 0.f, 0.f, 0.f};

  // staging: row-within-chunk = lane>>3, 16B piece j = lane&7.
  // Pre-swizzle k so LDS holds elem k at byte (k*2 ^ ((row&7)<<4)).
  int lr8 = lane >> 3;
  int jj = lane & 7;
  int ksrc = (jj ^ lr8) * 8;
  const unsigned short* gA = xb + (long)(brow + lr8) * I_ + ksrc;
  const unsigned short* gB = Wt + (long)(bcol + lr8) * K_ + e * I_ + ksrc;

  auto STAGE = [&](int buf, int s) {
    long kof = (long)s * BK;
#pragma unroll
    for (int i = 0; i < 4; ++i) {
      int chunk = i * 4 + wave;  // wave-uniform LDS base
      gload_lds16(gA + (long)chunk * 8 * I_ + kof, &As[buf][chunk * 512]);
      gload_lds16(gB + (long)chunk * 8 * K_ + kof, &Bs[buf][chunk * 512]);
    }
  };

  auto COMPUTE = [&](int buf) {
#pragma unroll
    for (int kk = 0; kk < 2; ++kk) {
      int kbyte = kk * 64 + (lane >> 4) * 16;  // byte offset of 8 bf16 along K
      short8 af[4], bfr[4];
#pragma unroll
      for (int m = 0; m < 4; ++m) {
        int r = wr * 64 + m * 16 + (lane & 15);
        int off = r * 64 + ((kbyte ^ ((r & 7) << 4)) >> 1);
        af[m] = *(const short8*)(&As[buf][off]);
      }
#pragma unroll
      for (int n = 0; n < 4; ++n) {
        int r = wc * 64 + n * 16 + (lane & 15);
        int off = r * 64 + ((kbyte ^ ((r & 7) << 4)) >> 1);
        bfr[n] = *(const short8*)(&Bs[buf][off]);
      }
#pragma unroll
      for (int m = 0; m < 4; ++m)
#pragma unroll
        for (int n = 0; n < 4; ++n)
          acc[m][n] = __builtin_amdgcn_mfma_f32_16x16x32_bf16(af[m], bfr[n], acc[m][n], 0, 0, 0);
    }
  };

  STAGE(0, 0);
  __syncthreads();
#pragma unroll
  for (int s = 0; s < NSTEP; ++s) {
    if (s + 1 < NSTEP) STAGE((s + 1) & 1, s + 1);  // prefetch BEFORE compute
    COMPUTE(s & 1);
    __syncthreads();
  }

  // C/D layout: col = lane&15, row = (lane>>4)*4 + reg
  int crow = wr * 64 + (lane >> 4) * 4;
  int ccol = wc * 64 + (lane & 15);
  if (USE_PART) {
    unsigned short* pb = part + (long)e * B_ * O_;
#pragma unroll
    for (int m = 0; m < 4; ++m)
#pragma unroll
      for (int n = 0; n < 4; ++n) {
        long rbase = (long)(brow + crow + m * 16) * O_ + bcol + ccol + n * 16;
#pragma unroll
        for (int j = 0; j < 4; ++j)
          pb[rbase + (long)j * O_] = f2bf(acc[m][n][j]);
      }
  } else {
    // atomic fallback: weight by c[row,e] here
#pragma unroll
    for (int m = 0; m < 4; ++m)
#pragma unroll
      for (int n = 0; n < 4; ++n) {
#pragma unroll
        for (int j = 0; j < 4; ++j) {
          int row = brow + crow + m * 16 + j;
          float c = coeffs[row * E_ + e];
          atomicAdd(out + (long)row * O_ + bcol + ccol + n * 16, c * acc[m][n][j]);
        }
      }
  }
}

// out[b][o] = sum_e c[b,e] * P[e][b][o] + sum_e c[b,e] * bias[e][o]
// (round-3-measured-best version: 4 outputs/thread, 512 blocks)
__global__ void combine_kernel(const unsigned short* __restrict__ part,
                               const float* __restrict__ coeffs,
                               const float* __restrict__ eb,
                               float* __restrict__ out) {
  int t = blockIdx.x * 256 + threadIdx.x;
  int b = t >> 7;
  int o4 = (t & 127) * 4;
  const float* cb = coeffs + b * E_;
  float4 acc = {0.f, 0.f, 0.f, 0.f};
#pragma unroll
  for (int e = 0; e < E_; ++e) {
    float c = cb[e];
    ushort4v v = *(const ushort4v*)(part + (long)e * B_ * O_ + (long)b * O_ + o4);
    acc.x += c * bf2f(v[0]); acc.y += c * bf2f(v[1]);
    acc.z += c * bf2f(v[2]); acc.w += c * bf2f(v[3]);
    float4 bv = *(const float4*)(eb + e * O_ + o4);
    acc.x += c * bv.x; acc.y += c * bv.y; acc.z += c * bv.z; acc.w += c * bv.w;
  }
  *(float4*)(out + (long)b * O_ + o4) = acc;
}

extern "C" void kernel_launch(void* const* d_in, const int* in_sizes, int n_in,
                              void* d_out, int out_size, void* d_ws, size_t ws_size,
                              hipStream_t stream) {
  const float* x      = (const float*)d_in[0];
  const float* coeffs = (const float*)d_in[1];
  const float* W      = (const float*)d_in[2];
  const float* eb     = (const float*)d_in[3];
  float* out = (float*)d_out;

  size_t xb_bytes   = (size_t)B_ * I_ * 2;        //  1 MiB
  size_t Wt_bytes   = (size_t)O_ * K_ * 2;        //  8 MiB
  size_t part_bytes = (size_t)E_ * B_ * O_ * 2;   // 16 MiB
  unsigned short* xb   = (unsigned short*)d_ws;
  unsigned short* Wt   = (unsigned short*)((char*)d_ws + xb_bytes);
  unsigned short* part = (unsigned short*)((char*)d_ws + xb_bytes + Wt_bytes);
  bool use_part = ws_size >= xb_bytes + Wt_bytes + part_bytes;

  prep_kernel<<<dim3(256 + 1024), 256, 0, stream>>>(x, W, xb, Wt);
  if (use_part) {
    gemm_kernel<1><<<dim3(NWG), 256, 0, stream>>>(xb, Wt, coeffs, out, part);
    combine_kernel<<<dim3(B_ * O_ / 4 / 256), 256, 0, stream>>>(part, coeffs, eb, out);
  } else {
    bias_init_kernel<<<dim3(B_ * O_ / 4 / 256), 256, 0, stream>>>(coeffs, eb, out);
    gemm_kernel<0><<<dim3(NWG), 256, 0, stream>>>(xb, Wt, coeffs, out, part);
  }
}